// Round 9
// baseline (64.819 us; speedup 1.0000x reference)
//
#include <hip/hip_runtime.h>
#include <stdint.h>

#define N      6144
#define F      128
#define D      32
#define H      4
#define HID    128
#define BINS   4096
#define RLO    (-6.0f)
#define INVW   (BINS / 12.0f)
#define NCP    80          // pref row stride in floats (320 B = 5 cache lines)
#define NROWS  (BINS + 1)

// ---- device scratch ----
__device__ __align__(16) float g_wht[(size_t)H * D * N];   // [h*32+d][N]
__device__ float g_es[H * N];
__device__ float g_td[H * N];
__device__ __align__(16) float g_pref[(size_t)H * NROWS * NCP];
__device__ float g_PART[48 * 32];
__device__ unsigned g_done;        // zero-init; self-resets each run

// ============ K1: pure GEMM -> WhT, es, td ============
__global__ __launch_bounds__(256) void k1_gemm(const float* __restrict__ x,
                                               const float* __restrict__ W,
                                               const float* __restrict__ a_src,
                                               const float* __restrict__ a_dst) {
    int tid  = threadIdx.x;
    int wv   = tid >> 6;
    int lane = tid & 63;
    int rg   = wv & 1;
    int ch   = wv >> 1;
    int row0 = __builtin_amdgcn_readfirstlane(blockIdx.x * 8 + rg * 4);
    int col  = ch * 64 + lane;     // 0..127
    int h    = col >> 5;
    int d    = col & 31;
    const float* __restrict__ xr = x + (size_t)row0 * F;
    const float* __restrict__ Wp = W + h * (F * D) + d;
    float acc[4] = {0.f, 0.f, 0.f, 0.f};
#pragma unroll 4
    for (int f = 0; f < F; ++f) {
        float w = Wp[f * D];
        acc[0] = fmaf(xr[f],         w, acc[0]);
        acc[1] = fmaf(xr[F + f],     w, acc[1]);
        acc[2] = fmaf(xr[2 * F + f], w, acc[2]);
        acc[3] = fmaf(xr[3 * F + f], w, acc[3]);
    }
    float as = a_src[col], ad = a_dst[col];
#pragma unroll
    for (int r = 0; r < 4; ++r) {
        int n = row0 + r;
        float ts = acc[r] * as, td = acc[r] * ad;
#pragma unroll
        for (int m = 1; m < 32; m <<= 1) {
            ts += __shfl_xor(ts, m);
            td += __shfl_xor(td, m);
        }
        if ((lane & 31) == 0) {
            g_es[h * N + n] = ts;
            g_td[h * N + n] = td;
        }
    }
    float4 w4;
    w4.x = acc[0]; w4.y = acc[1]; w4.z = acc[2]; w4.w = acc[3];
    *(float4*)&g_wht[(size_t)(h * 32 + d) * N + row0] = w4;
}

// ============ K2: per-(h,d) dual LDS histogram + fused scans ============
// blocks 0..127: (h,d) -> components c=d (e1*w) and c=32+d (e2*w)
// blocks 128..131: h scalars -> c=64 (e1), c=65 (e2)
__global__ __launch_bounds__(512) void k2_bin_scan() {
    __shared__ float binU[BINS];   // 16 KB
    __shared__ float binV[BINS];   // 16 KB
    __shared__ float tsum[512];
    int bidx = blockIdx.x;
    int tid = threadIdx.x;
    int h, cU, cV;
    const float* wcol = nullptr;
    if (bidx < 128) {
        h = bidx >> 5;
        int d = bidx & 31;
        cU = d; cV = 32 + d;
        wcol = g_wht + (size_t)(h * 32 + d) * N;
    } else {
        h = bidx - 128;
        cU = 64; cV = 65;
    }
    for (int i = tid; i < BINS; i += 512) { binU[i] = 0.f; binV[i] = 0.f; }
    __syncthreads();

    const float* tdp = g_td + h * N;
    if (wcol) {
        for (int n = tid; n < N; n += 512) {
            float t = tdp[n];
            float w = wcol[n];
            int b = (int)floorf((t - RLO) * INVW);
            b = min(max(b, 0), BINS - 1);
            atomicAdd(&binU[b], expf(0.01f * t) * w);
            atomicAdd(&binV[b], expf(t) * w);
        }
    } else {
        for (int n = tid; n < N; n += 512) {
            float t = tdp[n];
            int b = (int)floorf((t - RLO) * INVW);
            b = min(max(b, 0), BINS - 1);
            atomicAdd(&binU[b], expf(0.01f * t));
            atomicAdd(&binV[b], expf(t));
        }
    }
    __syncthreads();

    // two exclusive scans (4096 each, 8 elems/thread) -> pref columns
    float* hp = g_pref + (size_t)h * NROWS * NCP;
#pragma unroll
    for (int pass = 0; pass < 2; ++pass) {
        const float* bins = pass ? binV : binU;
        int c = pass ? cV : cU;
        int t0 = tid * 8;
        float incl[8];
        float run = 0.f;
#pragma unroll
        for (int j = 0; j < 8; ++j) { run += bins[t0 + j]; incl[j] = run; }
        tsum[tid] = run;
        for (int off = 1; off < 512; off <<= 1) {
            __syncthreads();
            float t = (tid >= off) ? tsum[tid - off] : 0.f;
            __syncthreads();
            tsum[tid] += t;
        }
        float offset = tsum[tid] - run;
        float* dst = hp + c;
        if (tid == 0) dst[0] = 0.f;
#pragma unroll
        for (int j = 0; j < 8; ++j)
            dst[(size_t)(t0 + j + 1) * NCP] = offset + incl[j];
        __syncthreads();
    }
}

// ============ K3: eval + fused finalize (last-block election) ============
__global__ __launch_bounds__(512) void k3_eval(const float* __restrict__ W_fc,
                                               const float* __restrict__ b_fc,
                                               float* __restrict__ out) {
    __shared__ float tot[68];
    __shared__ float wred[8][32];
    __shared__ float hm[HID];
    __shared__ unsigned s_rank;
    int bidx = blockIdx.x;             // 48 = H*12
    int h = bidx / 12;
    int tid = threadIdx.x;
    int lane = tid & 63, wv = tid >> 6;
    const float* hp = g_pref + (size_t)h * NROWS * NCP;
    if (tid < 68) tot[tid] = hp[(size_t)BINS * NCP + tid];
    __syncthreads();

    int i = (bidx % 12) * 512 + tid;
    float s = g_es[h * N + i];
    float th = -s;
    int idx = (int)floorf((th - RLO) * INVW);
    int row = min(max(idx + 1, 0), BINS);
    const float4* rp4 = (const float4*)(hp + (size_t)row * NCP);
    float e1 = expf(0.01f * s), e2 = expf(s);
    float4 sc = rp4[16];               // c=64..67 (64=u1, 65=v1)
    float denom = e1 * sc.x + e2 * (tot[65] - sc.y);
    float inv = 1.0f / denom;

    float av[32];
#pragma unroll
    for (int g = 0; g < 8; ++g) {
        float4 u4 = rp4[g];
        float4 v4 = rp4[8 + g];
        float us[4] = {u4.x, u4.y, u4.z, u4.w};
        float vs[4] = {v4.x, v4.y, v4.z, v4.w};
#pragma unroll
        for (int k = 0; k < 4; ++k) {
            int dd = g * 4 + k;
            float num = e1 * us[k] + e2 * (tot[32 + dd] - vs[k]);
            av[dd] = fmaxf(num, 0.f) * inv;   // relu(elu(x)) == relu(x); denom > 0
        }
    }
#pragma unroll
    for (int dd = 0; dd < 32; ++dd) {
#pragma unroll
        for (int m = 1; m < 64; m <<= 1) av[dd] += __shfl_xor(av[dd], m);
    }
    if (lane == 0) {
#pragma unroll
        for (int dd = 0; dd < 32; ++dd) wred[wv][dd] = av[dd];
    }
    __syncthreads();
    if (tid < 32) {
        float p = 0.f;
#pragma unroll
        for (int ww = 0; ww < 8; ++ww) p += wred[ww][tid];
        g_PART[bidx * 32 + tid] = p;
    }
    __syncthreads();
    if (tid == 0) {
        __builtin_amdgcn_fence(__ATOMIC_RELEASE, "agent");
        s_rank = __hip_atomic_fetch_add(&g_done, 1u,
                     __ATOMIC_ACQ_REL, __HIP_MEMORY_SCOPE_AGENT);
    }
    __syncthreads();
    if (s_rank == 47u) {               // unique last block finalizes
        __builtin_amdgcn_fence(__ATOMIC_ACQUIRE, "agent");
        if (tid < HID) {
            int hh = tid >> 5, dd = tid & 31;
            float sum = 0.f;
#pragma unroll
            for (int ch = 0; ch < 12; ++ch)
                sum += g_PART[((hh * 12 + ch) * 32) + dd];
            hm[tid] = sum * (1.0f / (float)N);
        }
        __syncthreads();
        if (tid < 128) {
            float y = b_fc[tid];
#pragma unroll 8
            for (int c = 0; c < 128; ++c)
                y = fmaf(hm[c], W_fc[c * 128 + tid], y);
            out[tid] = y;
        }
        if (tid == 0)
            __hip_atomic_store(&g_done, 0u,
                               __ATOMIC_RELAXED, __HIP_MEMORY_SCOPE_AGENT);
    }
}

extern "C" void kernel_launch(void* const* d_in, const int* in_sizes, int n_in,
                              void* d_out, int out_size, void* d_ws, size_t ws_size,
                              hipStream_t stream) {
    (void)in_sizes; (void)n_in; (void)d_ws; (void)ws_size; (void)out_size;
    const float* x     = (const float*)d_in[0];
    const float* W     = (const float*)d_in[1];
    const float* a_src = (const float*)d_in[2];
    const float* a_dst = (const float*)d_in[3];
    const float* W_fc  = (const float*)d_in[4];
    const float* b_fc  = (const float*)d_in[5];
    float* out = (float*)d_out;

    k1_gemm<<<dim3(N / 8), dim3(256), 0, stream>>>(x, W, a_src, a_dst);
    k2_bin_scan<<<dim3(132), dim3(512), 0, stream>>>();
    k3_eval<<<dim3(48), dim3(512), 0, stream>>>(W_fc, b_fc, out);
}

// Round 10
// 58.701 us; speedup vs baseline: 1.1042x; 1.1042x over previous
//
#include <hip/hip_runtime.h>
#include <stdint.h>

#define N      6144
#define F      128
#define D      32
#define H      4
#define HID    128
#define BINS   4096
#define RLO    (-6.0f)
#define INVW   (BINS / 12.0f)
#define NC     68          // 66 used components, padded to 68 (17 float4)
#define NROWS  (BINS + 1)

// ---- device scratch ----
__device__ __align__(16) float g_wht[(size_t)H * D * N];   // [h*32+d][N]
__device__ float g_es[H * N];
__device__ float g_e1[H * N];
__device__ float g_e2[H * N];
__device__ int   g_bin[H * N];
__device__ __align__(16) float g_pref[(size_t)H * NROWS * NC];
__device__ float g_PART[96 * 32];
__device__ unsigned g_done;        // zero-init; self-resets each run

// ============ K1: pure GEMM -> WhT, es, e1/e2/bin (no atomics) ============
__global__ __launch_bounds__(256) void k1_gemm(const float* __restrict__ x,
                                               const float* __restrict__ W,
                                               const float* __restrict__ a_src,
                                               const float* __restrict__ a_dst) {
    int tid  = threadIdx.x;
    int wv   = tid >> 6;
    int lane = tid & 63;
    int rg   = wv & 1;
    int ch   = wv >> 1;
    int row0 = __builtin_amdgcn_readfirstlane(blockIdx.x * 8 + rg * 4);
    int col  = ch * 64 + lane;     // 0..127
    int h    = col >> 5;
    int d    = col & 31;
    const float* __restrict__ xr = x + (size_t)row0 * F;
    const float* __restrict__ Wp = W + h * (F * D) + d;
    float acc[4] = {0.f, 0.f, 0.f, 0.f};
#pragma unroll 4
    for (int f = 0; f < F; ++f) {
        float w = Wp[f * D];
        acc[0] = fmaf(xr[f],         w, acc[0]);
        acc[1] = fmaf(xr[F + f],     w, acc[1]);
        acc[2] = fmaf(xr[2 * F + f], w, acc[2]);
        acc[3] = fmaf(xr[3 * F + f], w, acc[3]);
    }
    float as = a_src[col], ad = a_dst[col];
#pragma unroll
    for (int r = 0; r < 4; ++r) {
        int n = row0 + r;
        float ts = acc[r] * as, td = acc[r] * ad;
#pragma unroll
        for (int m = 1; m < 32; m <<= 1) {
            ts += __shfl_xor(ts, m);
            td += __shfl_xor(td, m);
        }
        if ((lane & 31) == 0) {
            g_es[h * N + n] = ts;
            float e1 = expf(0.01f * td);
            float e2 = expf(td);
            g_e1[h * N + n] = e1;
            g_e2[h * N + n] = e2;
            int b = (int)floorf((td - RLO) * INVW);
            g_bin[h * N + n] = min(max(b, 0), BINS - 1);
        }
    }
    float4 w4;
    w4.x = acc[0]; w4.y = acc[1]; w4.z = acc[2]; w4.w = acc[3];
    *(float4*)&g_wht[(size_t)(h * 32 + d) * N + row0] = w4;
}

// ============ K2: per-(h,c) LDS histogram + fused exclusive scan ============
__global__ __launch_bounds__(256) void k2_bin_scan() {
    __shared__ float bins[BINS];     // 16 KB private histogram
    __shared__ float tsum[256];
    int bidx = blockIdx.x;           // H*66
    int h = bidx / 66, c = bidx % 66;
    int tid = threadIdx.x;
    for (int i = tid; i < BINS; i += 256) bins[i] = 0.f;
    __syncthreads();

    const int*   bi = g_bin + h * N;
    const float* ev = (((c < 32) || (c == 64)) ? g_e1 : g_e2) + h * N;
    if (c < 64) {
        const float* wcol = g_wht + (size_t)(h * 32 + (c & 31)) * N;
        for (int n = tid; n < N; n += 256)
            atomicAdd(&bins[bi[n]], ev[n] * wcol[n]);
    } else {
        for (int n = tid; n < N; n += 256)
            atomicAdd(&bins[bi[n]], ev[n]);
    }
    __syncthreads();

    // exclusive scan of bins -> pref[h][b+1][c], pref[h][0][c] = 0
    int t0 = tid * 16;
    float incl[16];
    float run = 0.f;
#pragma unroll
    for (int j = 0; j < 16; ++j) { run += bins[t0 + j]; incl[j] = run; }
    tsum[tid] = run;
    for (int off = 1; off < 256; off <<= 1) {
        __syncthreads();
        float t = (tid >= off) ? tsum[tid - off] : 0.f;
        __syncthreads();
        tsum[tid] += t;
    }
    float offset = tsum[tid] - run;
    float* dst = g_pref + (size_t)h * NROWS * NC + c;
    if (tid == 0) dst[0] = 0.f;
#pragma unroll
    for (int j = 0; j < 16; ++j)
        dst[(size_t)(t0 + j + 1) * NC] = offset + incl[j];
}

// ============ K3: eval + fused finalize (last-block election) ============
__global__ __launch_bounds__(256) void k3_eval(const float* __restrict__ W_fc,
                                               const float* __restrict__ b_fc,
                                               float* __restrict__ out) {
    __shared__ float tot[NC];
    __shared__ float wred[4][32];
    __shared__ float hm[HID];
    __shared__ unsigned s_rank;
    int bidx = blockIdx.x;             // 96 = H*24
    int h = bidx / 24;
    int tid = threadIdx.x;
    int lane = tid & 63, wv = tid >> 6;
    const float* hp = g_pref + (size_t)h * NROWS * NC;
    if (tid < NC) tot[tid] = hp[(size_t)BINS * NC + tid];
    __syncthreads();

    int i = (bidx % 24) * 256 + tid;
    float s = g_es[h * N + i];
    float th = -s;
    int idx = (int)floorf((th - RLO) * INVW);
    int row = min(max(idx + 1, 0), BINS);
    const float4* rp4 = (const float4*)(hp + (size_t)row * NC);
    float e1 = expf(0.01f * s), e2 = expf(s);
    float4 sc = rp4[16];               // c=64..67 (64=u1, 65=v1)
    float denom = e1 * sc.x + e2 * (tot[65] - sc.y);
    float inv = 1.0f / denom;

    float av[32];
#pragma unroll
    for (int g = 0; g < 8; ++g) {
        float4 u4 = rp4[g];
        float4 v4 = rp4[8 + g];
        float us[4] = {u4.x, u4.y, u4.z, u4.w};
        float vs[4] = {v4.x, v4.y, v4.z, v4.w};
#pragma unroll
        for (int k = 0; k < 4; ++k) {
            int dd = g * 4 + k;
            float num = e1 * us[k] + e2 * (tot[32 + dd] - vs[k]);
            av[dd] = fmaxf(num, 0.f) * inv;   // relu(elu(x)) == relu(x); denom > 0
        }
    }
#pragma unroll
    for (int dd = 0; dd < 32; ++dd) {
#pragma unroll
        for (int m = 1; m < 64; m <<= 1) av[dd] += __shfl_xor(av[dd], m);
    }
    if (lane == 0) {
#pragma unroll
        for (int dd = 0; dd < 32; ++dd) wred[wv][dd] = av[dd];
    }
    __syncthreads();
    if (tid < 32)
        g_PART[bidx * 32 + tid] =
            wred[0][tid] + wred[1][tid] + wred[2][tid] + wred[3][tid];
    __syncthreads();
    if (tid == 0) {
        __builtin_amdgcn_fence(__ATOMIC_RELEASE, "agent");
        s_rank = __hip_atomic_fetch_add(&g_done, 1u,
                     __ATOMIC_ACQ_REL, __HIP_MEMORY_SCOPE_AGENT);
    }
    __syncthreads();
    if (s_rank == 95u) {               // unique last block finalizes
        __builtin_amdgcn_fence(__ATOMIC_ACQUIRE, "agent");
        if (tid < HID) {
            int hh = tid >> 5, dd = tid & 31;
            float sum = 0.f;
#pragma unroll
            for (int ch = 0; ch < 24; ++ch)
                sum += g_PART[((hh * 24 + ch) * 32) + dd];
            hm[tid] = sum * (1.0f / (float)N);
        }
        __syncthreads();
        if (tid < 128) {
            float y = b_fc[tid];
#pragma unroll 8
            for (int c = 0; c < 128; ++c)
                y = fmaf(hm[c], W_fc[c * 128 + tid], y);
            out[tid] = y;
        }
        if (tid == 0)
            __hip_atomic_store(&g_done, 0u,
                               __ATOMIC_RELAXED, __HIP_MEMORY_SCOPE_AGENT);
    }
}

extern "C" void kernel_launch(void* const* d_in, const int* in_sizes, int n_in,
                              void* d_out, int out_size, void* d_ws, size_t ws_size,
                              hipStream_t stream) {
    (void)in_sizes; (void)n_in; (void)d_ws; (void)ws_size; (void)out_size;
    const float* x     = (const float*)d_in[0];
    const float* W     = (const float*)d_in[1];
    const float* a_src = (const float*)d_in[2];
    const float* a_dst = (const float*)d_in[3];
    const float* W_fc  = (const float*)d_in[4];
    const float* b_fc  = (const float*)d_in[5];
    float* out = (float*)d_out;

    k1_gemm<<<dim3(N / 8), dim3(256), 0, stream>>>(x, W, a_src, a_dst);
    k2_bin_scan<<<dim3(H * 66), dim3(256), 0, stream>>>();
    k3_eval<<<dim3(96), dim3(256), 0, stream>>>(W_fc, b_fc, out);
}